// Round 7
// baseline (370.081 us; speedup 1.0000x reference)
//
#include <hip/hip_runtime.h>

#define N_NODES 131072
#define D 128
#define NLAYERS 4
#define VOCAB 320

typedef _Float16 f16;
typedef _Float16 f16x8 __attribute__((ext_vector_type(8)));
typedef float f32x4 __attribute__((ext_vector_type(4)));
typedef unsigned int u32;

// ---------- prep: fragment-ordered f16 weights + zero feat pad rows ----------
// W0f: frag(e,t,g,quad,lm,j) at ((e*4+t)*8+g)*512 + quad*128 + lm*8 + j
//   (k = e*128+t*32+quad*8+j, n = g*16+lm); lane reads base+lane*16B coalesced.
__global__ __launch_bounds__(256) void prep_wf(
    const float* __restrict__ W0, const float* __restrict__ W1,
    f16* __restrict__ W0f, f16* __restrict__ W1f,
    f16* __restrict__ fa, f16* __restrict__ fb)
{
    const int b = blockIdx.x, tid = threadIdx.x;
    if (b == 1280) {                    // zero pad row (id N_NODES) of both feat buffers
        if (tid < 32) {
            f16x8 z = {0, 0, 0, 0, 0, 0, 0, 0};
            f16* base = (tid >> 4) ? fb : fa;
            *(f16x8*)&base[(size_t)N_NODES * D + (tid & 15) * 8] = z;
        }
        return;
    }
    if (b < 1024) {                     // W0: 4 layers x 512 x 128
        int i = b * 256 + tid;
        int l = i >> 16, r = i & 65535;
        int k = r >> 7, n = r & 127;
        int e = k >> 7, t = (k >> 5) & 3, q = (k >> 3) & 3, j = k & 7;
        int g = n >> 4, lm = n & 15;
        int o = ((e * 4 + t) * 8 + g) * 512 + q * 128 + lm * 8 + j;
        W0f[(size_t)l * 65536 + o] = (f16)W0[i];
    } else {                            // W1: 4 layers x 128 x 128
        int i = (b - 1024) * 256 + tid;
        int l = i >> 14, r = i & 16383;
        int k = r >> 7, n = r & 127;
        int t = k >> 5, q = (k >> 3) & 3, j = k & 7;
        int g = n >> 4, lm = n & 15;
        int o = (t * 8 + g) * 512 + q * 128 + lm * 8 + j;
        W1f[(size_t)l * 16384 + o] = (f16)W1[i];
    }
}

// ---------- prep: embP[t] = f16(emb[t]); embP[VOCAB] = 0 ----------
__global__ __launch_bounds__(256) void prep_emb(
    const float* __restrict__ emb, f16* __restrict__ embP)
{
    const int tid = threadIdx.x;
    if (blockIdx.x == 40) {
        if (tid < 16) {
            f16x8 z = {0, 0, 0, 0, 0, 0, 0, 0};
            *(f16x8*)&embP[(size_t)VOCAB * D + tid * 8] = z;
        }
        return;
    }
    int i = blockIdx.x * 256 + tid;
    int t = i >> 5, c = i & 31;
    float4 x = ((const float4*)emb)[(size_t)t * 32 + c];
    f16 v[4] = {(f16)x.x, (f16)x.y, (f16)x.z, (f16)x.w};
    *(unsigned long long*)&embP[(size_t)t * D + c * 4] = *(unsigned long long*)v;
}

// ---------- prep: nbr_tok[v][e] = node_idx[neighbors[v][e]] (pad -> VOCAB) ----------
__global__ __launch_bounds__(256) void prep_nbrtok(
    const int* __restrict__ node_idx, const int* __restrict__ neighbors,
    int* __restrict__ nbr_tok)
{
    int i = blockIdx.x * 256 + threadIdx.x;
    int nbr = neighbors[i];
    nbr_tok[i] = (nbr < N_NODES) ? node_idx[nbr] : VOCAB;
}

#define NID(r, e) ((e) == 0 ? rn[r].x : (e) == 1 ? rn[r].y : (e) == 2 ? rn[r].z : rn[r].w)
#define LOAD_A(buf, s) { const int e_ = (s) >> 2, t_ = (s) & 3;              \
    _Pragma("unroll")                                                        \
    for (int r = 0; r < 4; ++r)                                              \
        af[buf][r] = *(const f16x8*)&fin[(size_t)NID(r, e_) * D + t_ * 32 + quad * 8]; }
#define LOAD_B(buf, s) {                                                     \
    _Pragma("unroll")                                                        \
    for (int c = 0; c < 2; ++c)                                              \
        bf[buf][c] = *(const f16x8*)&W0f[(size_t)((s) * 8 + wc * 2 + c) * 512 + lane * 8]; }

// ---------- fused layer: h=relu(gather(fin)@W0+b0); out=h@W1+b1 ----------
// BM=64, 4 waves x (64x32) tiles. Phase 1 barrier-free, A gathered straight
// into MFMA fragments (depth-2 prefetch), B from fragment-ordered weights.
// FINAL: emit per-segment fp32 means instead of feats.
template <bool FINAL>
__global__ __launch_bounds__(256, 4) void layer_k(
    const f16* __restrict__ fin, f16* __restrict__ fout,
    float* __restrict__ means, const int* __restrict__ nbrtab,
    const f16* __restrict__ W0f, const float* __restrict__ b0,
    const f16* __restrict__ W1f, const float* __restrict__ b1)
{
    __shared__ f16 As[64 * 128];        // 16 KB: phase-2 h tile (XOR-swizzled)

    const int tid  = threadIdx.x;
    const int bm   = blockIdx.x * 64;
    const int lane = tid & 63;
    const int wc   = tid >> 6;          // wave = column quarter
    const int quad = lane >> 4, lm = lane & 15;

    // neighbor ids for this lane's 4 rows (r*16+lm), all 4 slots as int4
    int4 rn[4];
#pragma unroll
    for (int r = 0; r < 4; ++r)
        rn[r] = *(const int4*)&nbrtab[(size_t)(bm + r * 16 + lm) * 4];

    float bb0[2], bb1[2];
#pragma unroll
    for (int c = 0; c < 2; ++c) {
        bb0[c] = b0[wc * 32 + c * 16 + lm];
        bb1[c] = b1[wc * 32 + c * 16 + lm];
    }

    f32x4 acc1[4][2];
#pragma unroll
    for (int r = 0; r < 4; ++r)
#pragma unroll
        for (int c = 0; c < 2; ++c) acc1[r][c] = (f32x4){0.f, 0.f, 0.f, 0.f};

    f16x8 af[3][4], bf[2][2];
    LOAD_B(0, 0)
    LOAD_A(0, 0)
    LOAD_A(1, 1)

    // ---- phase 1: K=512 as 16 frag-steps; barrier-free pipelined loads ----
#pragma unroll
    for (int s = 0; s < 16; ++s) {
        if (s < 15) LOAD_B((s + 1) & 1, s + 1)
        if (s < 14) LOAD_A((s + 2) % 3, s + 2)
#pragma unroll
        for (int r = 0; r < 4; ++r)
#pragma unroll
            for (int c = 0; c < 2; ++c)
                acc1[r][c] = __builtin_amdgcn_mfma_f32_16x16x32_f16(
                    af[s % 3][r], bf[s & 1][c], acc1[r][c], 0, 0, 0);
    }

    // ---- bias + relu -> h packed f16 pairs ----
    unsigned int hpk[4][2][2];
#pragma unroll
    for (int c = 0; c < 2; ++c)
#pragma unroll
        for (int r = 0; r < 4; ++r)
#pragma unroll
            for (int p = 0; p < 2; ++p) {
                float v0 = fmaxf(acc1[r][c][2 * p]     + bb0[c], 0.f);
                float v1 = fmaxf(acc1[r][c][2 * p + 1] + bb0[c], 0.f);
                unsigned short u0 = __builtin_bit_cast(unsigned short, (f16)v0);
                unsigned short u1 = __builtin_bit_cast(unsigned short, (f16)v1);
                hpk[r][c][p] = ((u32)u1 << 16) | u0;
            }

    // ---- scatter h (C-layout) into XOR-swizzled As ----
#pragma unroll
    for (int r = 0; r < 4; ++r)
#pragma unroll
        for (int c = 0; c < 2; ++c) {
            int gcol = wc * 32 + c * 16 + lm;
            int blk = gcol >> 3, el = gcol & 7;
#pragma unroll
            for (int reg = 0; reg < 4; ++reg) {
                int grow = r * 16 + quad * 4 + reg;
                unsigned pk = hpk[r][c][reg >> 1];
                unsigned short bits = (reg & 1) ? (unsigned short)(pk >> 16)
                                                : (unsigned short)(pk & 0xffff);
                As[grow * 128 + ((blk ^ (grow & 7)) * 8) + el] =
                    __builtin_bit_cast(f16, bits);
            }
        }

    f16x8 pbf[2][2];
#pragma unroll
    for (int c = 0; c < 2; ++c)
        pbf[0][c] = *(const f16x8*)&W1f[(size_t)(wc * 2 + c) * 512 + lane * 8];
    __syncthreads();                    // h visible

    // ---- phase 2: h @ W1, K=128 ----
    f32x4 acc2[4][2];
#pragma unroll
    for (int r = 0; r < 4; ++r)
#pragma unroll
        for (int c = 0; c < 2; ++c) acc2[r][c] = (f32x4){0.f, 0.f, 0.f, 0.f};

#pragma unroll
    for (int t = 0; t < 4; ++t) {
        if (t < 3) {
#pragma unroll
            for (int c = 0; c < 2; ++c)
                pbf[(t + 1) & 1][c] =
                    *(const f16x8*)&W1f[(size_t)((t + 1) * 8 + wc * 2 + c) * 512 + lane * 8];
        }
        f16x8 a2[4];
#pragma unroll
        for (int r = 0; r < 4; ++r) {
            int row = r * 16 + lm;
            a2[r] = *(const f16x8*)&As[row * 128 + (((4 * t + quad) ^ (lm & 7)) * 8)];
        }
#pragma unroll
        for (int r = 0; r < 4; ++r)
#pragma unroll
            for (int c = 0; c < 2; ++c)
                acc2[r][c] = __builtin_amdgcn_mfma_f32_16x16x32_f16(
                    a2[r], pbf[t & 1][c], acc2[r][c], 0, 0, 0);
    }

    if (FINAL) {
        // segment mean: this block IS one segment of 64 nodes
#pragma unroll
        for (int c = 0; c < 2; ++c) {
            float pc = 0.f;
#pragma unroll
            for (int r = 0; r < 4; ++r)
#pragma unroll
                for (int reg = 0; reg < 4; ++reg) pc += acc2[r][c][reg];
            pc += __shfl_xor(pc, 16);
            pc += __shfl_xor(pc, 32);
            if (quad == 0)
                means[(size_t)blockIdx.x * 128 + wc * 32 + c * 16 + lm] =
                    pc * (1.0f / 64.0f) + bb1[c];
        }
        return;
    }

    __syncthreads();                    // As reads done; reuse for epilogue
#pragma unroll
    for (int r = 0; r < 4; ++r)
#pragma unroll
        for (int c = 0; c < 2; ++c) {
            int gcol = wc * 32 + c * 16 + lm;
            int blk = gcol >> 3, el = gcol & 7;
#pragma unroll
            for (int reg = 0; reg < 4; ++reg) {
                int grow = r * 16 + quad * 4 + reg;
                As[grow * 128 + ((blk ^ (grow & 7)) * 8) + el] =
                    (f16)(acc2[r][c][reg] + bb1[c]);
            }
        }
    __syncthreads();
    {
        const int seg = tid & 15, r0 = tid >> 4;
#pragma unroll
        for (int i = 0; i < 4; ++i) {
            int row = r0 + 16 * i;
            *(f16x8*)&fout[(size_t)(bm + row) * D + seg * 8] =
                *(const f16x8*)&As[row * 128 + ((seg ^ (row & 7)) * 8)];
        }
    }
}

// ---------- final: logits[b] = dot(means[2b], means[2b+1]) + bias ----------
__global__ __launch_bounds__(256) void dot_k(
    const float* __restrict__ means, const float* __restrict__ out_bias,
    float* __restrict__ logits)
{
    const int w    = (blockIdx.x << 2) + (threadIdx.x >> 6);   // equation id
    const int lane = threadIdx.x & 63;
    const float2 a = *(const float2*)&means[(size_t)(2 * w) * 128 + lane * 2];
    const float2 b = *(const float2*)&means[(size_t)(2 * w + 1) * 128 + lane * 2];
    float v = a.x * b.x + a.y * b.y;
#pragma unroll
    for (int off = 32; off; off >>= 1) v += __shfl_down(v, off);
    if (lane == 0) logits[w] = v + out_bias[0];
}

extern "C" void kernel_launch(void* const* d_in, const int* in_sizes, int n_in,
                              void* d_out, int out_size, void* d_ws, size_t ws_size,
                              hipStream_t stream) {
    const int*   node_idx  = (const int*)d_in[0];
    const int*   neighbors = (const int*)d_in[1];
    const float* emb       = (const float*)d_in[3];
    const float* W0        = (const float*)d_in[4];
    const float* b0        = (const float*)d_in[5];
    const float* W1        = (const float*)d_in[6];
    const float* b1        = (const float*)d_in[7];
    const float* out_bias  = (const float*)d_in[8];
    float*       logits    = (float*)d_out;

    const size_t NP1 = (size_t)N_NODES + 1;                  // +1 zero pad row
    f16*   feats_a = (f16*)d_ws;                             // ~33.6 MB
    f16*   feats_b = feats_a + NP1 * D;                      // ~33.6 MB
    f16*   W0f     = feats_b + NP1 * D;                      // 512 KB
    f16*   W1f     = W0f + (size_t)NLAYERS * 512 * 128;      // 128 KB
    f16*   embP    = W1f + (size_t)NLAYERS * 128 * 128;      // ~82 KB
    int*   nbr_tok = (int*)(embP + (size_t)(VOCAB + 1) * D); // 2 MB
    float* means   = (float*)(nbr_tok + (size_t)N_NODES * 4);// 1 MB

    prep_wf<<<1281, 256, 0, stream>>>(W0, W1, W0f, W1f, feats_a, feats_b);
    prep_emb<<<41, 256, 0, stream>>>(emb, embP);
    prep_nbrtok<<<N_NODES * 4 / 256, 256, 0, stream>>>(node_idx, neighbors, nbr_tok);

    const int GRID = N_NODES / 64;      // 2048 blocks, 1 segment each

    // L0: embP-gather -> feats_a
    layer_k<false><<<GRID, 256, 0, stream>>>(
        embP, feats_a, nullptr, nbr_tok, W0f, b0, W1f, b1);
    // L1: a -> b
    layer_k<false><<<GRID, 256, 0, stream>>>(
        feats_a, feats_b, nullptr, neighbors,
        W0f + (size_t)1 * 65536, b0 + 128, W1f + (size_t)1 * 16384, b1 + 128);
    // L2: b -> a
    layer_k<false><<<GRID, 256, 0, stream>>>(
        feats_b, feats_a, nullptr, neighbors,
        W0f + (size_t)2 * 65536, b0 + 256, W1f + (size_t)2 * 16384, b1 + 256);
    // L3: a -> means (no feats write)
    layer_k<true><<<GRID, 256, 0, stream>>>(
        feats_a, nullptr, means, neighbors,
        W0f + (size_t)3 * 65536, b0 + 384, W1f + (size_t)3 * 16384, b1 + 384);

    dot_k<<<256, 256, 0, stream>>>(means, out_bias, logits);
}

// Round 8
// 205.502 us; speedup vs baseline: 1.8009x; 1.8009x over previous
//
#include <hip/hip_runtime.h>

#define N_NODES 131072
#define D 128
#define NLAYERS 4
#define VOCAB 320

typedef _Float16 f16;
typedef _Float16 f16x8 __attribute__((ext_vector_type(8)));
typedef float f32x4 __attribute__((ext_vector_type(4)));
typedef unsigned int u32;

// ---------- prep: fragment-ordered f16 weights + zero feat pad rows ----------
// W0f: frag(e,t,g,quad,lm,j) at ((e*4+t)*8+g)*512 + quad*128 + lm*8 + j
//   (k = e*128+t*32+quad*8+j, n = g*16+lm); lane reads base+lane*16B coalesced.
__global__ __launch_bounds__(256) void prep_wf(
    const float* __restrict__ W0, const float* __restrict__ W1,
    f16* __restrict__ W0f, f16* __restrict__ W1f,
    f16* __restrict__ fa, f16* __restrict__ fb)
{
    const int b = blockIdx.x, tid = threadIdx.x;
    if (b == 1280) {                    // zero pad row (id N_NODES) of both feat buffers
        if (tid < 32) {
            f16x8 z = {0, 0, 0, 0, 0, 0, 0, 0};
            f16* base = (tid >> 4) ? fb : fa;
            *(f16x8*)&base[(size_t)N_NODES * D + (tid & 15) * 8] = z;
        }
        return;
    }
    if (b < 1024) {                     // W0: 4 layers x 512 x 128
        int i = b * 256 + tid;
        int l = i >> 16, r = i & 65535;
        int k = r >> 7, n = r & 127;
        int e = k >> 7, t = (k >> 5) & 3, q = (k >> 3) & 3, j = k & 7;
        int g = n >> 4, lm = n & 15;
        int o = ((e * 4 + t) * 8 + g) * 512 + q * 128 + lm * 8 + j;
        W0f[(size_t)l * 65536 + o] = (f16)W0[i];
    } else {                            // W1: 4 layers x 128 x 128
        int i = (b - 1024) * 256 + tid;
        int l = i >> 14, r = i & 16383;
        int k = r >> 7, n = r & 127;
        int t = k >> 5, q = (k >> 3) & 3, j = k & 7;
        int g = n >> 4, lm = n & 15;
        int o = (t * 8 + g) * 512 + q * 128 + lm * 8 + j;
        W1f[(size_t)l * 16384 + o] = (f16)W1[i];
    }
}

// ---------- prep: embP[t] = f16(emb[t]); embP[VOCAB] = 0 ----------
__global__ __launch_bounds__(256) void prep_emb(
    const float* __restrict__ emb, f16* __restrict__ embP)
{
    const int tid = threadIdx.x;
    if (blockIdx.x == 40) {
        if (tid < 16) {
            f16x8 z = {0, 0, 0, 0, 0, 0, 0, 0};
            *(f16x8*)&embP[(size_t)VOCAB * D + tid * 8] = z;
        }
        return;
    }
    int i = blockIdx.x * 256 + tid;
    int t = i >> 5, c = i & 31;
    float4 x = ((const float4*)emb)[(size_t)t * 32 + c];
    f16 v[4] = {(f16)x.x, (f16)x.y, (f16)x.z, (f16)x.w};
    *(unsigned long long*)&embP[(size_t)t * D + c * 4] = *(unsigned long long*)v;
}

// ---------- prep: nbr_tok[v][e] = node_idx[neighbors[v][e]] (pad -> VOCAB) ----------
__global__ __launch_bounds__(256) void prep_nbrtok(
    const int* __restrict__ node_idx, const int* __restrict__ neighbors,
    int* __restrict__ nbr_tok)
{
    int i = blockIdx.x * 256 + threadIdx.x;
    int nbr = neighbors[i];
    nbr_tok[i] = (nbr < N_NODES) ? node_idx[nbr] : VOCAB;
}

#define NID4(v, e) ((e) == 0 ? (v).x : (e) == 1 ? (v).y : (e) == 2 ? (v).z : (v).w)
// stage-load: 16-lane group (r0) owns rows r0,r0+16,..; lane kb loads 16B block kb
#define SLOAD(e_) {                                                          \
    _Pragma("unroll")                                                        \
    for (int i = 0; i < 4; ++i)                                              \
        sg[i] = *(const f16x8*)&fin[(size_t)NID4(rn4[i], e_) * D + kb * 8]; }
// stage-store: XOR-swizzled 16B blocks; per 16-lane group = full row -> conflict-free
#define SSTORE(buf) {                                                        \
    _Pragma("unroll")                                                        \
    for (int i = 0; i < 4; ++i) {                                            \
        int row = r0 + 16 * i;                                               \
        *(f16x8*)&As[buf][row * 128 + ((kb ^ (row & 7)) * 8)] = sg[i];       \
    } }
#define LOAD_B(buf, s) {                                                     \
    _Pragma("unroll")                                                        \
    for (int c = 0; c < 2; ++c)                                              \
        bf[buf][c] = *(const f16x8*)&W0f[(size_t)((s) * 8 + w * 2 + c) * 512 + lane * 8]; }

// ---------- fused layer: h=relu(gather(fin)@W0+b0); out=h@W1+b1 ----------
// BM=64, 4 waves x (64 rows x 32 cols). A staged once per block (1x redundancy)
// into double-buffered LDS with a full-stage prefetch distance; B direct from
// fragment-ordered L2-hot weights. FINAL: emit per-segment fp32 means.
template <bool FINAL>
__global__ __launch_bounds__(256, 4) void layer_k(
    const f16* __restrict__ fin, f16* __restrict__ fout,
    float* __restrict__ means, const int* __restrict__ nbrtab,
    const f16* __restrict__ W0f, const float* __restrict__ b0,
    const f16* __restrict__ W1f, const float* __restrict__ b1)
{
    __shared__ f16 As[2][64 * 128];     // 2 x 16 KB, XOR-swizzled 16B blocks

    const int tid  = threadIdx.x;
    const int bm   = blockIdx.x * 64;
    const int lane = tid & 63;
    const int w    = tid >> 6;          // wave = column quarter (cols w*32..)
    const int quad = lane >> 4, lm = lane & 15;
    const int kb   = tid & 15;          // 16B block this thread stages
    const int r0   = tid >> 4;          // base row this thread stages

    // neighbor ids (all 4 slots) for this thread's 4 staging rows
    int4 rn4[4];
#pragma unroll
    for (int i = 0; i < 4; ++i)
        rn4[i] = *(const int4*)&nbrtab[(size_t)(bm + r0 + 16 * i) * 4];

    float bb0[2], bb1[2];
#pragma unroll
    for (int c = 0; c < 2; ++c) {
        bb0[c] = b0[w * 32 + c * 16 + lm];
        bb1[c] = b1[w * 32 + c * 16 + lm];
    }

    f16x8 sg[4], bf[2][2];
    SLOAD(0)
    SSTORE(0)
    LOAD_B(0, 0)
    __syncthreads();

    f32x4 acc1[4][2];
#pragma unroll
    for (int r = 0; r < 4; ++r)
#pragma unroll
        for (int c = 0; c < 2; ++c) acc1[r][c] = (f32x4){0.f, 0.f, 0.f, 0.f};

    // ---- phase 1: 4 stages of K=128; gather prefetched one full stage ahead ----
#pragma unroll
    for (int e = 0; e < 4; ++e) {
        if (e < 3) SLOAD(e + 1)                  // in flight across whole compute
#pragma unroll
        for (int t = 0; t < 4; ++t) {
            const int s = e * 4 + t;
            if (s < 15) LOAD_B((s + 1) & 1, s + 1)
            f16x8 af[4];
#pragma unroll
            for (int r = 0; r < 4; ++r) {
                int row = r * 16 + lm;
                af[r] = *(const f16x8*)&As[e & 1][row * 128 + (((t * 4 + quad) ^ (lm & 7)) * 8)];
            }
#pragma unroll
            for (int r = 0; r < 4; ++r)
#pragma unroll
                for (int c = 0; c < 2; ++c)
                    acc1[r][c] = __builtin_amdgcn_mfma_f32_16x16x32_f16(
                        af[r], bf[s & 1][c], acc1[r][c], 0, 0, 0);
        }
        if (e < 3) {
            SSTORE((e + 1) & 1)                  // vmcnt wait lands here
            __syncthreads();
        }
    }

    // ---- bias + relu -> h packed f16 pairs ----
    unsigned int hpk[4][2][2];
#pragma unroll
    for (int c = 0; c < 2; ++c)
#pragma unroll
        for (int r = 0; r < 4; ++r)
#pragma unroll
            for (int p = 0; p < 2; ++p) {
                float v0 = fmaxf(acc1[r][c][2 * p]     + bb0[c], 0.f);
                float v1 = fmaxf(acc1[r][c][2 * p + 1] + bb0[c], 0.f);
                unsigned short u0 = __builtin_bit_cast(unsigned short, (f16)v0);
                unsigned short u1 = __builtin_bit_cast(unsigned short, (f16)v1);
                hpk[r][c][p] = ((u32)u1 << 16) | u0;
            }

    // ---- scatter h (C-layout) into XOR-swizzled As[0] (free since e=2 barrier) ----
#pragma unroll
    for (int r = 0; r < 4; ++r)
#pragma unroll
        for (int c = 0; c < 2; ++c) {
            int gcol = w * 32 + c * 16 + lm;
            int blk = gcol >> 3, el = gcol & 7;
#pragma unroll
            for (int reg = 0; reg < 4; ++reg) {
                int grow = r * 16 + quad * 4 + reg;
                unsigned pk = hpk[r][c][reg >> 1];
                unsigned short bits = (reg & 1) ? (unsigned short)(pk >> 16)
                                                : (unsigned short)(pk & 0xffff);
                As[0][grow * 128 + ((blk ^ (grow & 7)) * 8) + el] =
                    __builtin_bit_cast(f16, bits);
            }
        }

    f16x8 pbf[2][2];
#pragma unroll
    for (int c = 0; c < 2; ++c)
        pbf[0][c] = *(const f16x8*)&W1f[(size_t)(w * 2 + c) * 512 + lane * 8];
    __syncthreads();                    // h visible

    // ---- phase 2: h @ W1, K=128 ----
    f32x4 acc2[4][2];
#pragma unroll
    for (int r = 0; r < 4; ++r)
#pragma unroll
        for (int c = 0; c < 2; ++c) acc2[r][c] = (f32x4){0.f, 0.f, 0.f, 0.f};

#pragma unroll
    for (int t = 0; t < 4; ++t) {
        if (t < 3) {
#pragma unroll
            for (int c = 0; c < 2; ++c)
                pbf[(t + 1) & 1][c] =
                    *(const f16x8*)&W1f[(size_t)((t + 1) * 8 + w * 2 + c) * 512 + lane * 8];
        }
        f16x8 a2[4];
#pragma unroll
        for (int r = 0; r < 4; ++r) {
            int row = r * 16 + lm;
            a2[r] = *(const f16x8*)&As[0][row * 128 + (((4 * t + quad) ^ (lm & 7)) * 8)];
        }
#pragma unroll
        for (int r = 0; r < 4; ++r)
#pragma unroll
            for (int c = 0; c < 2; ++c)
                acc2[r][c] = __builtin_amdgcn_mfma_f32_16x16x32_f16(
                    a2[r], pbf[t & 1][c], acc2[r][c], 0, 0, 0);
    }

    if (FINAL) {
        // this block IS one segment of 64 nodes -> fp32 mean per column
#pragma unroll
        for (int c = 0; c < 2; ++c) {
            float pc = 0.f;
#pragma unroll
            for (int r = 0; r < 4; ++r)
#pragma unroll
                for (int reg = 0; reg < 4; ++reg) pc += acc2[r][c][reg];
            pc += __shfl_xor(pc, 16);
            pc += __shfl_xor(pc, 32);
            if (quad == 0)
                means[(size_t)blockIdx.x * 128 + w * 32 + c * 16 + lm] =
                    pc * (1.0f / 64.0f) + bb1[c];
        }
        return;
    }

    // ---- epilogue: bias -> swizzled As[1] -> coalesced 16B stores ----
#pragma unroll
    for (int r = 0; r < 4; ++r)
#pragma unroll
        for (int c = 0; c < 2; ++c) {
            int gcol = w * 32 + c * 16 + lm;
            int blk = gcol >> 3, el = gcol & 7;
#pragma unroll
            for (int reg = 0; reg < 4; ++reg) {
                int grow = r * 16 + quad * 4 + reg;
                As[1][grow * 128 + ((blk ^ (grow & 7)) * 8) + el] =
                    (f16)(acc2[r][c][reg] + bb1[c]);
            }
        }
    __syncthreads();
#pragma unroll
    for (int i = 0; i < 4; ++i) {
        int row = r0 + 16 * i;
        *(f16x8*)&fout[(size_t)(bm + row) * D + kb * 8] =
            *(const f16x8*)&As[1][row * 128 + ((kb ^ (row & 7)) * 8)];
    }
}

// ---------- final: logits[b] = dot(means[2b], means[2b+1]) + bias ----------
__global__ __launch_bounds__(256) void dot_k(
    const float* __restrict__ means, const float* __restrict__ out_bias,
    float* __restrict__ logits)
{
    const int w    = (blockIdx.x << 2) + (threadIdx.x >> 6);   // equation id
    const int lane = threadIdx.x & 63;
    const float2 a = *(const float2*)&means[(size_t)(2 * w) * 128 + lane * 2];
    const float2 b = *(const float2*)&means[(size_t)(2 * w + 1) * 128 + lane * 2];
    float v = a.x * b.x + a.y * b.y;
#pragma unroll
    for (int off = 32; off; off >>= 1) v += __shfl_down(v, off);
    if (lane == 0) logits[w] = v + out_bias[0];
}

extern "C" void kernel_launch(void* const* d_in, const int* in_sizes, int n_in,
                              void* d_out, int out_size, void* d_ws, size_t ws_size,
                              hipStream_t stream) {
    const int*   node_idx  = (const int*)d_in[0];
    const int*   neighbors = (const int*)d_in[1];
    const float* emb       = (const float*)d_in[3];
    const float* W0        = (const float*)d_in[4];
    const float* b0        = (const float*)d_in[5];
    const float* W1        = (const float*)d_in[6];
    const float* b1        = (const float*)d_in[7];
    const float* out_bias  = (const float*)d_in[8];
    float*       logits    = (float*)d_out;

    const size_t NP1 = (size_t)N_NODES + 1;                  // +1 zero pad row
    f16*   feats_a = (f16*)d_ws;                             // ~33.6 MB
    f16*   feats_b = feats_a + NP1 * D;                      // ~33.6 MB
    f16*   W0f     = feats_b + NP1 * D;                      // 512 KB
    f16*   W1f     = W0f + (size_t)NLAYERS * 512 * 128;      // 128 KB
    f16*   embP    = W1f + (size_t)NLAYERS * 128 * 128;      // ~82 KB
    int*   nbr_tok = (int*)(embP + (size_t)(VOCAB + 1) * D); // 2 MB
    float* means   = (float*)(nbr_tok + (size_t)N_NODES * 4);// 1 MB

    prep_wf<<<1281, 256, 0, stream>>>(W0, W1, W0f, W1f, feats_a, feats_b);
    prep_emb<<<41, 256, 0, stream>>>(emb, embP);
    prep_nbrtok<<<N_NODES * 4 / 256, 256, 0, stream>>>(node_idx, neighbors, nbr_tok);

    const int GRID = N_NODES / 64;      // 2048 blocks, 1 segment each

    layer_k<false><<<GRID, 256, 0, stream>>>(
        embP, feats_a, nullptr, nbr_tok, W0f, b0, W1f, b1);
    layer_k<false><<<GRID, 256, 0, stream>>>(
        feats_a, feats_b, nullptr, neighbors,
        W0f + (size_t)1 * 65536, b0 + 128, W1f + (size_t)1 * 16384, b1 + 128);
    layer_k<false><<<GRID, 256, 0, stream>>>(
        feats_b, feats_a, nullptr, neighbors,
        W0f + (size_t)2 * 65536, b0 + 256, W1f + (size_t)2 * 16384, b1 + 256);
    layer_k<true><<<GRID, 256, 0, stream>>>(
        feats_a, nullptr, means, neighbors,
        W0f + (size_t)3 * 65536, b0 + 384, W1f + (size_t)3 * 16384, b1 + 384);

    dot_k<<<256, 256, 0, stream>>>(means, out_bias, logits);
}

// Round 9
// 199.773 us; speedup vs baseline: 1.8525x; 1.0287x over previous
//
#include <hip/hip_runtime.h>

#define N_NODES 131072
#define D 128
#define NLAYERS 4
#define VOCAB 320

typedef _Float16 f16;
typedef _Float16 f16x8 __attribute__((ext_vector_type(8)));
typedef float f32x4 __attribute__((ext_vector_type(4)));
typedef unsigned int u32;

// ---------- prep: fragment-ordered f16 weights + zero feat pad rows ----------
// W0f: frag(e,t,g,quad,lm,j) at ((e*4+t)*8+g)*512 + quad*128 + lm*8 + j
//   (k = e*128+t*32+quad*8+j, n = g*16+lm); lane reads base+lane*16B coalesced.
__global__ __launch_bounds__(256) void prep_wf(
    const float* __restrict__ W0, const float* __restrict__ W1,
    f16* __restrict__ W0f, f16* __restrict__ W1f,
    f16* __restrict__ fa, f16* __restrict__ fb)
{
    const int b = blockIdx.x, tid = threadIdx.x;
    if (b == 1280) {                    // zero pad row (id N_NODES) of both feat buffers
        if (tid < 32) {
            f16x8 z = {0, 0, 0, 0, 0, 0, 0, 0};
            f16* base = (tid >> 4) ? fb : fa;
            *(f16x8*)&base[(size_t)N_NODES * D + (tid & 15) * 8] = z;
        }
        return;
    }
    if (b < 1024) {                     // W0: 4 layers x 512 x 128
        int i = b * 256 + tid;
        int l = i >> 16, r = i & 65535;
        int k = r >> 7, n = r & 127;
        int e = k >> 7, t = (k >> 5) & 3, q = (k >> 3) & 3, j = k & 7;
        int g = n >> 4, lm = n & 15;
        int o = ((e * 4 + t) * 8 + g) * 512 + q * 128 + lm * 8 + j;
        W0f[(size_t)l * 65536 + o] = (f16)W0[i];
    } else {                            // W1: 4 layers x 128 x 128
        int i = (b - 1024) * 256 + tid;
        int l = i >> 14, r = i & 16383;
        int k = r >> 7, n = r & 127;
        int t = k >> 5, q = (k >> 3) & 3, j = k & 7;
        int g = n >> 4, lm = n & 15;
        int o = (t * 8 + g) * 512 + q * 128 + lm * 8 + j;
        W1f[(size_t)l * 16384 + o] = (f16)W1[i];
    }
}

// ---------- prep: embP[t] = f16(emb[t]); embP[VOCAB] = 0 ----------
__global__ __launch_bounds__(256) void prep_emb(
    const float* __restrict__ emb, f16* __restrict__ embP)
{
    const int tid = threadIdx.x;
    if (blockIdx.x == 40) {
        if (tid < 16) {
            f16x8 z = {0, 0, 0, 0, 0, 0, 0, 0};
            *(f16x8*)&embP[(size_t)VOCAB * D + tid * 8] = z;
        }
        return;
    }
    int i = blockIdx.x * 256 + tid;
    int t = i >> 5, c = i & 31;
    float4 x = ((const float4*)emb)[(size_t)t * 32 + c];
    f16 v[4] = {(f16)x.x, (f16)x.y, (f16)x.z, (f16)x.w};
    *(unsigned long long*)&embP[(size_t)t * D + c * 4] = *(unsigned long long*)v;
}

// ---------- prep: nbr_tok[v][e] = node_idx[neighbors[v][e]] (pad -> VOCAB) ----------
__global__ __launch_bounds__(256) void prep_nbrtok(
    const int* __restrict__ node_idx, const int* __restrict__ neighbors,
    int* __restrict__ nbr_tok)
{
    int i = blockIdx.x * 256 + threadIdx.x;
    int nbr = neighbors[i];
    nbr_tok[i] = (nbr < N_NODES) ? node_idx[nbr] : VOCAB;
}

#define NID4(v, e) ((e) == 0 ? (v).x : (e) == 1 ? (v).y : (e) == 2 ? (v).z : (v).w)
// stage-load: thread (kb,r0) owns rows r0,r0+16,..; lane kb loads 16B block kb
#define SLOAD(e_) {                                                          \
    _Pragma("unroll")                                                        \
    for (int i = 0; i < 4; ++i)                                              \
        sg[i] = *(const f16x8*)&fin[(size_t)NID4(rn4[i], e_) * D + kb * 8]; }
// stage-store: XOR-swizzled 16B blocks; 16-lane group = full row -> conflict-free
#define SSTORE(buf) {                                                        \
    _Pragma("unroll")                                                        \
    for (int i = 0; i < 4; ++i) {                                            \
        int row = r0 + 16 * i;                                               \
        *(f16x8*)&As[buf][row * 128 + ((kb ^ (row & 7)) * 8)] = sg[i];       \
    } }
#define LOAD_B(buf, s) {                                                     \
    _Pragma("unroll")                                                        \
    for (int c = 0; c < 2; ++c)                                              \
        bf[buf][c] = *(const f16x8*)&W0f[(size_t)((s) * 8 + w * 2 + c) * 512 + lane * 8]; }

// ---------- fused layer: h=relu(gather(fin)@W0+b0); out=h@W1+b1 ----------
// BM=64, 4 waves x (64 rows x 32 cols). A staged once per block (1x redundancy)
// into double-buffered LDS, full-stage gather prefetch; B direct from
// fragment-ordered weights at prefetch distance 3 (covers L2 latency).
// FINAL: emit per-segment fp32 means.
template <bool FINAL>
__global__ __launch_bounds__(256, 4) void layer_k(
    const f16* __restrict__ fin, f16* __restrict__ fout,
    float* __restrict__ means, const int* __restrict__ nbrtab,
    const f16* __restrict__ W0f, const float* __restrict__ b0,
    const f16* __restrict__ W1f, const float* __restrict__ b1)
{
    __shared__ f16 As[2][64 * 128];     // 2 x 16 KB, XOR-swizzled 16B blocks

    const int tid  = threadIdx.x;
    const int bm   = blockIdx.x * 64;
    const int lane = tid & 63;
    const int w    = tid >> 6;          // wave = column quarter (cols w*32..)
    const int quad = lane >> 4, lm = lane & 15;
    const int kb   = tid & 15;          // 16B block this thread stages
    const int r0   = tid >> 4;          // base row this thread stages

    // neighbor ids (all 4 slots) for this thread's 4 staging rows
    int4 rn4[4];
#pragma unroll
    for (int i = 0; i < 4; ++i)
        rn4[i] = *(const int4*)&nbrtab[(size_t)(bm + r0 + 16 * i) * 4];

    float bb0[2], bb1[2];
#pragma unroll
    for (int c = 0; c < 2; ++c) {
        bb0[c] = b0[w * 32 + c * 16 + lm];
        bb1[c] = b1[w * 32 + c * 16 + lm];
    }

    f16x8 sg[4], bf[4][2];
    SLOAD(0)
    LOAD_B(0, 0)                        // B loads issue before the SSTORE stall
    LOAD_B(1, 1)
    LOAD_B(2, 2)
    SSTORE(0)                           // waits only on sg (oldest loads)
    __syncthreads();

    f32x4 acc1[4][2];
#pragma unroll
    for (int r = 0; r < 4; ++r)
#pragma unroll
        for (int c = 0; c < 2; ++c) acc1[r][c] = (f32x4){0.f, 0.f, 0.f, 0.f};

    // ---- phase 1: 4 stages of K=128; gather one full stage ahead, B 3 steps ----
#pragma unroll
    for (int e = 0; e < 4; ++e) {
        if (e < 3) SLOAD(e + 1)                  // in flight across whole compute
#pragma unroll
        for (int t = 0; t < 4; ++t) {
            const int s = e * 4 + t;
            if (s < 13) LOAD_B((s + 3) & 3, s + 3)
            f16x8 af[4];
#pragma unroll
            for (int r = 0; r < 4; ++r) {
                int row = r * 16 + lm;
                af[r] = *(const f16x8*)&As[e & 1][row * 128 + (((t * 4 + quad) ^ (lm & 7)) * 8)];
            }
#pragma unroll
            for (int r = 0; r < 4; ++r)
#pragma unroll
                for (int c = 0; c < 2; ++c)
                    acc1[r][c] = __builtin_amdgcn_mfma_f32_16x16x32_f16(
                        af[r], bf[s & 3][c], acc1[r][c], 0, 0, 0);
        }
        if (e < 3) {
            SSTORE((e + 1) & 1)                  // vmcnt wait lands here
            __syncthreads();
        }
    }

    // ---- bias + relu -> h packed f16 pairs ----
    unsigned int hpk[4][2][2];
#pragma unroll
    for (int c = 0; c < 2; ++c)
#pragma unroll
        for (int r = 0; r < 4; ++r)
#pragma unroll
            for (int p = 0; p < 2; ++p) {
                float v0 = fmaxf(acc1[r][c][2 * p]     + bb0[c], 0.f);
                float v1 = fmaxf(acc1[r][c][2 * p + 1] + bb0[c], 0.f);
                unsigned short u0 = __builtin_bit_cast(unsigned short, (f16)v0);
                unsigned short u1 = __builtin_bit_cast(unsigned short, (f16)v1);
                hpk[r][c][p] = ((u32)u1 << 16) | u0;
            }

    // ---- scatter h (C-layout) into XOR-swizzled As[0] ----
#pragma unroll
    for (int r = 0; r < 4; ++r)
#pragma unroll
        for (int c = 0; c < 2; ++c) {
            int gcol = w * 32 + c * 16 + lm;
            int blk = gcol >> 3, el = gcol & 7;
#pragma unroll
            for (int reg = 0; reg < 4; ++reg) {
                int grow = r * 16 + quad * 4 + reg;
                unsigned pk = hpk[r][c][reg >> 1];
                unsigned short bits = (reg & 1) ? (unsigned short)(pk >> 16)
                                                : (unsigned short)(pk & 0xffff);
                As[0][grow * 128 + ((blk ^ (grow & 7)) * 8) + el] =
                    __builtin_bit_cast(f16, bits);
            }
        }

    // preload ALL phase-2 B frags; latency hides under the barrier
    f16x8 pbf[4][2];
#pragma unroll
    for (int t = 0; t < 4; ++t)
#pragma unroll
        for (int c = 0; c < 2; ++c)
            pbf[t][c] = *(const f16x8*)&W1f[(size_t)(t * 8 + w * 2 + c) * 512 + lane * 8];
    __syncthreads();                    // h visible

    // ---- phase 2: h @ W1, K=128 ----
    f32x4 acc2[4][2];
#pragma unroll
    for (int r = 0; r < 4; ++r)
#pragma unroll
        for (int c = 0; c < 2; ++c) acc2[r][c] = (f32x4){0.f, 0.f, 0.f, 0.f};

#pragma unroll
    for (int t = 0; t < 4; ++t) {
        f16x8 a2[4];
#pragma unroll
        for (int r = 0; r < 4; ++r) {
            int row = r * 16 + lm;
            a2[r] = *(const f16x8*)&As[0][row * 128 + (((4 * t + quad) ^ (lm & 7)) * 8)];
        }
#pragma unroll
        for (int r = 0; r < 4; ++r)
#pragma unroll
            for (int c = 0; c < 2; ++c)
                acc2[r][c] = __builtin_amdgcn_mfma_f32_16x16x32_f16(
                    a2[r], pbf[t][c], acc2[r][c], 0, 0, 0);
    }

    if (FINAL) {
        // this block IS one segment of 64 nodes -> fp32 mean per column
#pragma unroll
        for (int c = 0; c < 2; ++c) {
            float pc = 0.f;
#pragma unroll
            for (int r = 0; r < 4; ++r)
#pragma unroll
                for (int reg = 0; reg < 4; ++reg) pc += acc2[r][c][reg];
            pc += __shfl_xor(pc, 16);
            pc += __shfl_xor(pc, 32);
            if (quad == 0)
                means[(size_t)blockIdx.x * 128 + w * 32 + c * 16 + lm] =
                    pc * (1.0f / 64.0f) + bb1[c];
        }
        return;
    }

    // ---- epilogue: bias -> swizzled As[1] -> coalesced 16B stores ----
    __syncthreads();                    // As[1] reads finished in phase 1? (e=3 read As[1])
#pragma unroll
    for (int r = 0; r < 4; ++r)
#pragma unroll
        for (int c = 0; c < 2; ++c) {
            int gcol = w * 32 + c * 16 + lm;
            int blk = gcol >> 3, el = gcol & 7;
#pragma unroll
            for (int reg = 0; reg < 4; ++reg) {
                int grow = r * 16 + quad * 4 + reg;
                As[1][grow * 128 + ((blk ^ (grow & 7)) * 8) + el] =
                    (f16)(acc2[r][c][reg] + bb1[c]);
            }
        }
    __syncthreads();
#pragma unroll
    for (int i = 0; i < 4; ++i) {
        int row = r0 + 16 * i;
        *(f16x8*)&fout[(size_t)(bm + row) * D + kb * 8] =
            *(const f16x8*)&As[1][row * 128 + ((kb ^ (row & 7)) * 8)];
    }
}

// ---------- final: logits[b] = dot(means[2b], means[2b+1]) + bias ----------
__global__ __launch_bounds__(256) void dot_k(
    const float* __restrict__ means, const float* __restrict__ out_bias,
    float* __restrict__ logits)
{
    const int w    = (blockIdx.x << 2) + (threadIdx.x >> 6);   // equation id
    const int lane = threadIdx.x & 63;
    const float2 a = *(const float2*)&means[(size_t)(2 * w) * 128 + lane * 2];
    const float2 b = *(const float2*)&means[(size_t)(2 * w + 1) * 128 + lane * 2];
    float v = a.x * b.x + a.y * b.y;
#pragma unroll
    for (int off = 32; off; off >>= 1) v += __shfl_down(v, off);
    if (lane == 0) logits[w] = v + out_bias[0];
}

extern "C" void kernel_launch(void* const* d_in, const int* in_sizes, int n_in,
                              void* d_out, int out_size, void* d_ws, size_t ws_size,
                              hipStream_t stream) {
    const int*   node_idx  = (const int*)d_in[0];
    const int*   neighbors = (const int*)d_in[1];
    const float* emb       = (const float*)d_in[3];
    const float* W0        = (const float*)d_in[4];
    const float* b0        = (const float*)d_in[5];
    const float* W1        = (const float*)d_in[6];
    const float* b1        = (const float*)d_in[7];
    const float* out_bias  = (const float*)d_in[8];
    float*       logits    = (float*)d_out;

    const size_t NP1 = (size_t)N_NODES + 1;                  // +1 zero pad row
    f16*   feats_a = (f16*)d_ws;                             // ~33.6 MB
    f16*   feats_b = feats_a + NP1 * D;                      // ~33.6 MB
    f16*   W0f     = feats_b + NP1 * D;                      // 512 KB
    f16*   W1f     = W0f + (size_t)NLAYERS * 512 * 128;      // 128 KB
    f16*   embP    = W1f + (size_t)NLAYERS * 128 * 128;      // ~82 KB
    int*   nbr_tok = (int*)(embP + (size_t)(VOCAB + 1) * D); // 2 MB
    float* means   = (float*)(nbr_tok + (size_t)N_NODES * 4);// 1 MB

    prep_wf<<<1281, 256, 0, stream>>>(W0, W1, W0f, W1f, feats_a, feats_b);
    prep_emb<<<41, 256, 0, stream>>>(emb, embP);
    prep_nbrtok<<<N_NODES * 4 / 256, 256, 0, stream>>>(node_idx, neighbors, nbr_tok);

    const int GRID = N_NODES / 64;      // 2048 blocks, 1 segment each

    layer_k<false><<<GRID, 256, 0, stream>>>(
        embP, feats_a, nullptr, nbr_tok, W0f, b0, W1f, b1);
    layer_k<false><<<GRID, 256, 0, stream>>>(
        feats_a, feats_b, nullptr, neighbors,
        W0f + (size_t)1 * 65536, b0 + 128, W1f + (size_t)1 * 16384, b1 + 128);
    layer_k<false><<<GRID, 256, 0, stream>>>(
        feats_b, feats_a, nullptr, neighbors,
        W0f + (size_t)2 * 65536, b0 + 256, W1f + (size_t)2 * 16384, b1 + 256);
    layer_k<true><<<GRID, 256, 0, stream>>>(
        feats_a, nullptr, means, neighbors,
        W0f + (size_t)3 * 65536, b0 + 384, W1f + (size_t)3 * 16384, b1 + 384);

    dot_k<<<256, 256, 0, stream>>>(means, out_bias, logits);
}

// Round 10
// 198.599 us; speedup vs baseline: 1.8635x; 1.0059x over previous
//
#include <hip/hip_runtime.h>

#define N_NODES 131072
#define D 128
#define NLAYERS 4
#define VOCAB 320

typedef _Float16 f16;
typedef _Float16 f16x8 __attribute__((ext_vector_type(8)));
typedef float f32x4 __attribute__((ext_vector_type(4)));
typedef unsigned int u32;

// ---------- prep (single kernel): fragment-ordered weights, f16 emb, nbr tokens ----------
// W0f: frag(e,t,g,quad,lm,j) at ((e*4+t)*8+g)*512 + quad*128 + lm*8 + j
//   (k = e*128+t*32+quad*8+j, n = g*16+lm); lane reads base+lane*16B coalesced.
__global__ __launch_bounds__(256) void prep_all(
    const float* __restrict__ W0, const float* __restrict__ W1,
    const float* __restrict__ emb, const int* __restrict__ node_idx,
    const int* __restrict__ neighbors,
    f16* __restrict__ W0f, f16* __restrict__ W1f, f16* __restrict__ embP,
    int* __restrict__ nbr_tok, f16* __restrict__ fa, f16* __restrict__ fb)
{
    const int b = blockIdx.x, tid = threadIdx.x;
    if (b < 1024) {                     // W0: 4 layers x 512 x 128
        int i = b * 256 + tid;
        int l = i >> 16, r = i & 65535;
        int k = r >> 7, n = r & 127;
        int e = k >> 7, t = (k >> 5) & 3, q = (k >> 3) & 3, j = k & 7;
        int g = n >> 4, lm = n & 15;
        int o = ((e * 4 + t) * 8 + g) * 512 + q * 128 + lm * 8 + j;
        W0f[(size_t)l * 65536 + o] = (f16)W0[i];
    } else if (b < 1280) {              // W1: 4 layers x 128 x 128
        int i = (b - 1024) * 256 + tid;
        int l = i >> 14, r = i & 16383;
        int k = r >> 7, n = r & 127;
        int t = k >> 5, q = (k >> 3) & 3, j = k & 7;
        int g = n >> 4, lm = n & 15;
        int o = (t * 8 + g) * 512 + q * 128 + lm * 8 + j;
        W1f[(size_t)l * 16384 + o] = (f16)W1[i];
    } else if (b == 1280) {             // zero pad row (id N_NODES) of both feat buffers
        if (tid < 32) {
            f16x8 z = {0, 0, 0, 0, 0, 0, 0, 0};
            f16* base = (tid >> 4) ? fb : fa;
            *(f16x8*)&base[(size_t)N_NODES * D + (tid & 15) * 8] = z;
        }
    } else if (b < 1322) {              // embP = f16(emb); embP[VOCAB] = 0
        if (b == 1321) {
            if (tid < 16) {
                f16x8 z = {0, 0, 0, 0, 0, 0, 0, 0};
                *(f16x8*)&embP[(size_t)VOCAB * D + tid * 8] = z;
            }
            return;
        }
        int i = (b - 1281) * 256 + tid; // VOCAB*32 float4 groups
        int t = i >> 5, c = i & 31;
        float4 x = ((const float4*)emb)[(size_t)t * 32 + c];
        f16 v[4] = {(f16)x.x, (f16)x.y, (f16)x.z, (f16)x.w};
        *(unsigned long long*)&embP[(size_t)t * D + c * 4] = *(unsigned long long*)v;
    } else {                            // nbr_tok[v][e] = node_idx[neighbors[v][e]]
        int i = (b - 1322) * 256 + tid; // N*4
        int nbr = neighbors[i];
        nbr_tok[i] = (nbr < N_NODES) ? node_idx[nbr] : VOCAB;
    }
}

#define NID4(v, e) ((e) == 0 ? (v).x : (e) == 1 ? (v).y : (e) == 2 ? (v).z : (v).w)
// stage-load into register buffer `buf`: thread (kb,r0) owns rows r0,r0+16,..
#define SLOAD(buf, e_) {                                                     \
    _Pragma("unroll")                                                        \
    for (int i = 0; i < 4; ++i)                                              \
        sg[buf][i] = *(const f16x8*)&fin[(size_t)NID4(rn4[i], e_) * D + kb * 8]; }
// stage-store: XOR-swizzled 16B blocks; 16-lane group = full row -> conflict-free
#define SSTORE(buf, ab) {                                                    \
    _Pragma("unroll")                                                        \
    for (int i = 0; i < 4; ++i) {                                            \
        int row = r0 + 16 * i;                                               \
        *(f16x8*)&As[ab][row * 128 + ((kb ^ (row & 7)) * 8)] = sg[buf][i];   \
    } }
#define LOAD_B(buf, s) {                                                     \
    _Pragma("unroll")                                                        \
    for (int c = 0; c < 2; ++c)                                              \
        bf[buf][c] = *(const f16x8*)&W0f[(size_t)((s) * 8 + w * 2 + c) * 512 + lane * 8]; }

// ---------- fused layer: h=relu(gather(fin)@W0+b0); out=h@W1+b1 ----------
// BM=64, 4 waves x (64 rows x 32 cols). A staged once per block (1x redundancy)
// into double-buffered LDS. Gather register-prefetch distance = 2 FULL stages
// (covers ~900-cyc HBM-miss latency); B direct from fragment-ordered weights
// at distance 3. FINAL: emit per-segment fp32 means.
template <bool FINAL>
__global__ __launch_bounds__(256, 4) void layer_k(
    const f16* __restrict__ fin, f16* __restrict__ fout,
    float* __restrict__ means, const int* __restrict__ nbrtab,
    const f16* __restrict__ W0f, const float* __restrict__ b0,
    const f16* __restrict__ W1f, const float* __restrict__ b1)
{
    __shared__ f16 As[2][64 * 128];     // 2 x 16 KB, XOR-swizzled 16B blocks

    const int tid  = threadIdx.x;
    const int bm   = blockIdx.x * 64;
    const int lane = tid & 63;
    const int w    = tid >> 6;          // wave = column quarter (cols w*32..)
    const int quad = lane >> 4, lm = lane & 15;
    const int kb   = tid & 15;          // 16B block this thread stages
    const int r0   = tid >> 4;          // base row this thread stages

    // neighbor ids (all 4 slots) for this thread's 4 staging rows
    int4 rn4[4];
#pragma unroll
    for (int i = 0; i < 4; ++i)
        rn4[i] = *(const int4*)&nbrtab[(size_t)(bm + r0 + 16 * i) * 4];

    float bb0[2], bb1[2];
#pragma unroll
    for (int c = 0; c < 2; ++c) {
        bb0[c] = b0[w * 32 + c * 16 + lm];
        bb1[c] = b1[w * 32 + c * 16 + lm];
    }

    f16x8 sg[2][4], bf[4][2];
    SLOAD(0, 0)                         // slot-0 gathers (oldest)
    SLOAD(1, 1)                         // slot-1 gathers: in flight 2 stages deep
    LOAD_B(0, 0)                        // B issues before the SSTORE stall
    LOAD_B(1, 1)
    LOAD_B(2, 2)
    SSTORE(0, 0)                        // waits only on slot-0 loads
    __syncthreads();

    f32x4 acc1[4][2];
#pragma unroll
    for (int r = 0; r < 4; ++r)
#pragma unroll
        for (int c = 0; c < 2; ++c) acc1[r][c] = (f32x4){0.f, 0.f, 0.f, 0.f};

    // ---- phase 1: 4 stages of K=128; gather 2 stages ahead, B 3 t-steps ----
#pragma unroll
    for (int e = 0; e < 4; ++e) {
        if (e < 2) SLOAD(e & 1, e + 2)           // refill buffer just stored
#pragma unroll
        for (int t = 0; t < 4; ++t) {
            const int s = e * 4 + t;
            if (s < 13) LOAD_B((s + 3) & 3, s + 3)
            f16x8 af[4];
#pragma unroll
            for (int r = 0; r < 4; ++r) {
                int row = r * 16 + lm;
                af[r] = *(const f16x8*)&As[e & 1][row * 128 + (((t * 4 + quad) ^ (lm & 7)) * 8)];
            }
#pragma unroll
            for (int r = 0; r < 4; ++r)
#pragma unroll
                for (int c = 0; c < 2; ++c)
                    acc1[r][c] = __builtin_amdgcn_mfma_f32_16x16x32_f16(
                        af[r], bf[s & 3][c], acc1[r][c], 0, 0, 0);
        }
        if (e < 3) {
            SSTORE((e + 1) & 1, (e + 1) & 1)     // data loaded ~2 stages ago
            __syncthreads();
        }
    }

    // ---- bias + relu -> h packed f16 pairs ----
    unsigned int hpk[4][2][2];
#pragma unroll
    for (int c = 0; c < 2; ++c)
#pragma unroll
        for (int r = 0; r < 4; ++r)
#pragma unroll
            for (int p = 0; p < 2; ++p) {
                float v0 = fmaxf(acc1[r][c][2 * p]     + bb0[c], 0.f);
                float v1 = fmaxf(acc1[r][c][2 * p + 1] + bb0[c], 0.f);
                unsigned short u0 = __builtin_bit_cast(unsigned short, (f16)v0);
                unsigned short u1 = __builtin_bit_cast(unsigned short, (f16)v1);
                hpk[r][c][p] = ((u32)u1 << 16) | u0;
            }

    // ---- scatter h (C-layout) into XOR-swizzled As[0] ----
#pragma unroll
    for (int r = 0; r < 4; ++r)
#pragma unroll
        for (int c = 0; c < 2; ++c) {
            int gcol = w * 32 + c * 16 + lm;
            int blk = gcol >> 3, el = gcol & 7;
#pragma unroll
            for (int reg = 0; reg < 4; ++reg) {
                int grow = r * 16 + quad * 4 + reg;
                unsigned pk = hpk[r][c][reg >> 1];
                unsigned short bits = (reg & 1) ? (unsigned short)(pk >> 16)
                                                : (unsigned short)(pk & 0xffff);
                As[0][grow * 128 + ((blk ^ (grow & 7)) * 8) + el] =
                    __builtin_bit_cast(f16, bits);
            }
        }

    // preload ALL phase-2 B frags; latency hides under the barrier
    f16x8 pbf[4][2];
#pragma unroll
    for (int t = 0; t < 4; ++t)
#pragma unroll
        for (int c = 0; c < 2; ++c)
            pbf[t][c] = *(const f16x8*)&W1f[(size_t)(t * 8 + w * 2 + c) * 512 + lane * 8];
    __syncthreads();                    // h visible

    // ---- phase 2: h @ W1, K=128 ----
    f32x4 acc2[4][2];
#pragma unroll
    for (int r = 0; r < 4; ++r)
#pragma unroll
        for (int c = 0; c < 2; ++c) acc2[r][c] = (f32x4){0.f, 0.f, 0.f, 0.f};

#pragma unroll
    for (int t = 0; t < 4; ++t) {
        f16x8 a2[4];
#pragma unroll
        for (int r = 0; r < 4; ++r) {
            int row = r * 16 + lm;
            a2[r] = *(const f16x8*)&As[0][row * 128 + (((4 * t + quad) ^ (lm & 7)) * 8)];
        }
#pragma unroll
        for (int r = 0; r < 4; ++r)
#pragma unroll
            for (int c = 0; c < 2; ++c)
                acc2[r][c] = __builtin_amdgcn_mfma_f32_16x16x32_f16(
                    a2[r], pbf[t][c], acc2[r][c], 0, 0, 0);
    }

    if (FINAL) {
        // this block IS one segment of 64 nodes -> fp32 mean per column
#pragma unroll
        for (int c = 0; c < 2; ++c) {
            float pc = 0.f;
#pragma unroll
            for (int r = 0; r < 4; ++r)
#pragma unroll
                for (int reg = 0; reg < 4; ++reg) pc += acc2[r][c][reg];
            pc += __shfl_xor(pc, 16);
            pc += __shfl_xor(pc, 32);
            if (quad == 0)
                means[(size_t)blockIdx.x * 128 + w * 32 + c * 16 + lm] =
                    pc * (1.0f / 64.0f) + bb1[c];
        }
        return;
    }

    // ---- epilogue: bias -> swizzled As[1] -> coalesced 16B stores ----
    __syncthreads();
#pragma unroll
    for (int r = 0; r < 4; ++r)
#pragma unroll
        for (int c = 0; c < 2; ++c) {
            int gcol = w * 32 + c * 16 + lm;
            int blk = gcol >> 3, el = gcol & 7;
#pragma unroll
            for (int reg = 0; reg < 4; ++reg) {
                int grow = r * 16 + quad * 4 + reg;
                As[1][grow * 128 + ((blk ^ (grow & 7)) * 8) + el] =
                    (f16)(acc2[r][c][reg] + bb1[c]);
            }
        }
    __syncthreads();
#pragma unroll
    for (int i = 0; i < 4; ++i) {
        int row = r0 + 16 * i;
        *(f16x8*)&fout[(size_t)(bm + row) * D + kb * 8] =
            *(const f16x8*)&As[1][row * 128 + ((kb ^ (row & 7)) * 8)];
    }
}

// ---------- final: logits[b] = dot(means[2b], means[2b+1]) + bias ----------
__global__ __launch_bounds__(256) void dot_k(
    const float* __restrict__ means, const float* __restrict__ out_bias,
    float* __restrict__ logits)
{
    const int w    = (blockIdx.x << 2) + (threadIdx.x >> 6);   // equation id
    const int lane = threadIdx.x & 63;
    const float2 a = *(const float2*)&means[(size_t)(2 * w) * 128 + lane * 2];
    const float2 b = *(const float2*)&means[(size_t)(2 * w + 1) * 128 + lane * 2];
    float v = a.x * b.x + a.y * b.y;
#pragma unroll
    for (int off = 32; off; off >>= 1) v += __shfl_down(v, off);
    if (lane == 0) logits[w] = v + out_bias[0];
}

extern "C" void kernel_launch(void* const* d_in, const int* in_sizes, int n_in,
                              void* d_out, int out_size, void* d_ws, size_t ws_size,
                              hipStream_t stream) {
    const int*   node_idx  = (const int*)d_in[0];
    const int*   neighbors = (const int*)d_in[1];
    const float* emb       = (const float*)d_in[3];
    const float* W0        = (const float*)d_in[4];
    const float* b0        = (const float*)d_in[5];
    const float* W1        = (const float*)d_in[6];
    const float* b1        = (const float*)d_in[7];
    const float* out_bias  = (const float*)d_in[8];
    float*       logits    = (float*)d_out;

    const size_t NP1 = (size_t)N_NODES + 1;                  // +1 zero pad row
    f16*   feats_a = (f16*)d_ws;                             // ~33.6 MB
    f16*   feats_b = feats_a + NP1 * D;                      // ~33.6 MB
    f16*   W0f     = feats_b + NP1 * D;                      // 512 KB
    f16*   W1f     = W0f + (size_t)NLAYERS * 512 * 128;      // 128 KB
    f16*   embP    = W1f + (size_t)NLAYERS * 128 * 128;      // ~82 KB
    int*   nbr_tok = (int*)(embP + (size_t)(VOCAB + 1) * D); // 2 MB
    float* means   = (float*)(nbr_tok + (size_t)N_NODES * 4);// 1 MB

    prep_all<<<1322 + N_NODES * 4 / 256, 256, 0, stream>>>(
        W0, W1, emb, node_idx, neighbors, W0f, W1f, embP, nbr_tok,
        feats_a, feats_b);

    const int GRID = N_NODES / 64;      // 2048 blocks, 1 segment each

    layer_k<false><<<GRID, 256, 0, stream>>>(
        embP, feats_a, nullptr, nbr_tok, W0f, b0, W1f, b1);
    layer_k<false><<<GRID, 256, 0, stream>>>(
        feats_a, feats_b, nullptr, neighbors,
        W0f + (size_t)1 * 65536, b0 + 128, W1f + (size_t)1 * 16384, b1 + 128);
    layer_k<false><<<GRID, 256, 0, stream>>>(
        feats_b, feats_a, nullptr, neighbors,
        W0f + (size_t)2 * 65536, b0 + 256, W1f + (size_t)2 * 16384, b1 + 256);
    layer_k<true><<<GRID, 256, 0, stream>>>(
        feats_a, nullptr, means, neighbors,
        W0f + (size_t)3 * 65536, b0 + 384, W1f + (size_t)3 * 16384, b1 + 384);

    dot_k<<<256, 256, 0, stream>>>(means, out_bias, logits);
}